// Round 1
// baseline (531.146 us; speedup 1.0000x reference)
//
#include <hip/hip_runtime.h>

// LSTMDiscriminator: B=256, T=1024, I=200, H=16
// K1: x_proj[b,t,g] = x[b,t,:] @ W_ih[g,:] + b_ih[g] + b_hh[g], stored permuted
//     so that K2's lane reads column `lane` where gate-row r = (lane&3)*16 + (lane>>2).
// K2: fused LSTM scan + head (relu(h@W1^T+b1) @ W2^T + b2 -> sigmoid -> mean over T).

#define T_LEN 1024
#define NB    256

#define F2I(x) __float_as_int(x)
#define I2F(x) __int_as_float(x)

// DPP helper: broadcast/rotate within rows. ctrl is a compile-time constant.
#define DPPF(v, ctrl) I2F(__builtin_amdgcn_update_dpp(F2I(v), F2I(v), (ctrl), 0xF, 0xF, false))
// readlane -> wave-uniform (SGPR) float
#define RDLANE(v, l) I2F(__builtin_amdgcn_readlane(F2I(v), (l)))

__device__ __forceinline__ float fast_sigmoid(float x) {
  float e = __expf(-x);
  return __fdividef(1.0f, 1.0f + e);
}

// ---------------- Kernel 1: input projection ----------------
// grid = 4096 blocks x 64 threads. Block handles 64 rows (row = b*T + t).
// lane = permuted output column; all x loads are blockIdx-uniform -> s_load.
__global__ __launch_bounds__(64) void k1_xproj(
    const float* __restrict__ x, const float* __restrict__ Wih,
    const float* __restrict__ bih, const float* __restrict__ bhh,
    float* __restrict__ xproj)
{
  const int lane = threadIdx.x;                    // 0..63
  const int r = ((lane & 3) << 4) | (lane >> 2);   // gate row in [0,64)
  const long row0 = (long)blockIdx.x * 64;

  const float bias = bih[r] + bhh[r];
  float acc[64];
#pragma unroll
  for (int i = 0; i < 64; ++i) acc[i] = bias;

  const float* wrow = Wih + (long)r * 200;

#pragma unroll 1
  for (int c = 0; c < 6; ++c) {               // 6 chunks of 32 (k = 0..191)
    float4 w[8];
#pragma unroll
    for (int q = 0; q < 8; ++q)
      w[q] = *reinterpret_cast<const float4*>(wrow + c * 32 + q * 4);
#pragma unroll
    for (int i = 0; i < 64; ++i) {
      const float4* xr = reinterpret_cast<const float4*>(x + (row0 + i) * 200 + c * 32);
      float s0 = 0.f, s1 = 0.f, s2 = 0.f, s3 = 0.f;
#pragma unroll
      for (int q = 0; q < 8; ++q) {
        float4 xa = xr[q];                     // wave-uniform -> scalar load
        s0 = fmaf(xa.x, w[q].x, s0);
        s1 = fmaf(xa.y, w[q].y, s1);
        s2 = fmaf(xa.z, w[q].z, s2);
        s3 = fmaf(xa.w, w[q].w, s3);
      }
      acc[i] += (s0 + s1) + (s2 + s3);
    }
  }
  { // tail k = 192..199 (exact reads, no OOB)
    float4 w0 = *reinterpret_cast<const float4*>(wrow + 192);
    float4 w1 = *reinterpret_cast<const float4*>(wrow + 196);
#pragma unroll
    for (int i = 0; i < 64; ++i) {
      const float4* xr = reinterpret_cast<const float4*>(x + (row0 + i) * 200 + 192);
      float4 a0 = xr[0], a1 = xr[1];
      acc[i] += a0.x * w0.x + a0.y * w0.y + a0.z * w0.z + a0.w * w0.w
              + a1.x * w1.x + a1.y * w1.y + a1.z * w1.z + a1.w * w1.w;
    }
  }
#pragma unroll
  for (int i = 0; i < 64; ++i)
    xproj[(row0 + i) * 64 + lane] = acc[i];    // coalesced, permuted layout
}

// ---------------- Kernel 2: fused LSTM scan + head ----------------
// grid = 256 blocks x 64 threads; one wave per batch row -> 1 wave/CU.
// lane: j = lane>>2 (hidden unit), g = lane&3 (gate: 0=i,1=f,2=g,3=o).
__global__ __launch_bounds__(64, 1) void k2_scan(
    const float* __restrict__ xproj,
    const float* __restrict__ h0, const float* __restrict__ c0,
    const float* __restrict__ Whh,
    const float* __restrict__ W1, const float* __restrict__ b1,
    const float* __restrict__ W2, const float* __restrict__ b2,
    float* __restrict__ out)
{
  const int b = blockIdx.x;
  const int lane = threadIdx.x;
  const int g = lane & 3;
  const int j = lane >> 2;
  const int r = (g << 4) | j;

  float whh[16];
#pragma unroll
  for (int q = 0; q < 4; ++q) {
    float4 w = *reinterpret_cast<const float4*>(Whh + r * 16 + q * 4);
    whh[q * 4 + 0] = w.x; whh[q * 4 + 1] = w.y;
    whh[q * 4 + 2] = w.z; whh[q * 4 + 3] = w.w;
  }
  float w1row[16];
#pragma unroll
  for (int k = 0; k < 16; ++k) w1row[k] = W1[j * 16 + k];
  const float w2j = W2[j];
  const float b1j = b1[j];
  const float b2s = b2[0];

  float c = c0[b * 16 + j];
  float hmine = h0[b * 16 + j];
  float hs[16];                    // wave-uniform h, lives in SGPRs
#pragma unroll
  for (int k = 0; k < 16; ++k) hs[k] = RDLANE(hmine, 4 * k);

  const float mfac = (g == 2) ? -2.f : -1.f;   // exp argument scale
  const float pfac = (g == 2) ?  2.f :  1.f;   // tanh = 2*sig(2x)-1
  const float qfac = (g == 2) ? -1.f :  0.f;

  const float* xp = xproj + (size_t)b * (T_LEN * 64) + lane;
  float buf[8];                    // 8-deep prefetch, static-indexed
#pragma unroll
  for (int u = 0; u < 8; ++u) buf[u] = xp[(size_t)u * 64];

  float accs = 0.f;

  for (int tb = 0; tb < T_LEN; tb += 8) {
#pragma unroll
    for (int u = 0; u < 8; ++u) {
      const float gin = buf[u];
      int tn = tb + 8 + u;
      tn = (tn < T_LEN) ? tn : (T_LEN - 8 + u);      // clamp (dead loads at end)
      buf[u] = xp[(size_t)tn * 64];

      // gate pre-activation: gin + sum_k Whh[r,k] * h[k]  (h in SGPRs)
      float pre = gin;
#pragma unroll
      for (int k = 0; k < 16; ++k) pre = fmaf(whh[k], hs[k], pre);

      // unified sigmoid/tanh: y = pfac * sigmoid(-mfac*pre... ) + qfac
      float e = __expf(mfac * pre);
      float z = __fdividef(1.f, 1.f + e);
      float y = fmaf(pfac, z, qfac);

      // broadcast the 4 gate activations within each quad (DPP, no LDS)
      float ai = DPPF(y, 0x00);   // quad_perm [0,0,0,0]
      float af = DPPF(y, 0x55);   // quad_perm [1,1,1,1]
      float ag = DPPF(y, 0xAA);   // quad_perm [2,2,2,2]
      float ao = DPPF(y, 0xFF);   // quad_perm [3,3,3,3]

      c = fmaf(af, c, ai * ag);
      float e2 = __expf(-2.f * c);
      float th = fmaf(2.f, __fdividef(1.f, 1.f + e2), -1.f);
      float h = ao * th;

      // broadcast new h to SGPRs (lane 4k holds h[k])
#pragma unroll
      for (int k = 0; k < 16; ++k) hs[k] = RDLANE(h, 4 * k);

      // ---- head (off critical path) ----
      float p1 = b1j;
#pragma unroll
      for (int k = 0; k < 16; ++k) p1 = fmaf(w1row[k], hs[k], p1);
      p1 = fmaxf(p1, 0.f);
      float pl = p1 * w2j;        // quad-uniform value per j

      // sum over the 16 distinct j's (each quad counted once by rotation sums)
      float v = pl;
      v = v + DPPF(v, 0x124);     // row_ror:4
      v = v + DPPF(v, 0x128);     // row_ror:8  -> row (16-lane) quad-sum
      v = v + I2F(__builtin_amdgcn_ds_swizzle(F2I(v), 0x401F));  // xor 16
      v = v + __shfl_xor(v, 32, 64);                              // xor 32

      float s2 = b2s + v;
      accs += fast_sigmoid(s2);
    }
  }

  if (lane == 0) out[b] = accs * (1.0f / T_LEN);
}

// ---------------- launcher ----------------
extern "C" void kernel_launch(void* const* d_in, const int* in_sizes, int n_in,
                              void* d_out, int out_size, void* d_ws, size_t ws_size,
                              hipStream_t stream) {
  const float* x   = (const float*)d_in[0];
  const float* h0  = (const float*)d_in[1];
  const float* c0  = (const float*)d_in[2];
  const float* Wih = (const float*)d_in[3];
  const float* Whh = (const float*)d_in[4];
  const float* bih = (const float*)d_in[5];
  const float* bhh = (const float*)d_in[6];
  const float* W1  = (const float*)d_in[7];
  const float* b1  = (const float*)d_in[8];
  const float* W2  = (const float*)d_in[9];
  const float* b2  = (const float*)d_in[10];

  float* xproj = (float*)d_ws;   // needs 256*1024*64*4 = 64 MiB of scratch

  hipLaunchKernelGGL(k1_xproj, dim3(4096), dim3(64), 0, stream,
                     x, Wih, bih, bhh, xproj);
  hipLaunchKernelGGL(k2_scan, dim3(NB), dim3(64), 0, stream,
                     xproj, h0, c0, Whh, W1, b1, W2, b2, (float*)d_out);
}

// Round 2
// 490.201 us; speedup vs baseline: 1.0835x; 1.0835x over previous
//
#include <hip/hip_runtime.h>

// LSTMDiscriminator: B=256, T=1024, I=200, H=16
// K1: x_proj[b,t,col] = x[b,t,:] @ W_ih[r(col),:] + b_ih[r] + b_hh[r], bf16,
//     permuted so K2 lane reads col=lane with gate-row r = ((lane&3)<<4)|(lane>>2).
//     Structure: 64-row tile staged in LDS (coalesced), x read back as
//     same-address ds_read_b128 broadcasts; W chunk in per-lane VGPRs.
// K2: fused LSTM scan + head; tree-structured recurrent dot to cut dep chain.

#define T_LEN 1024
#define NB    256

#define F2I(x) __float_as_int(x)
#define I2F(x) __int_as_float(x)

#define DPPF(v, ctrl) I2F(__builtin_amdgcn_update_dpp(F2I(v), F2I(v), (ctrl), 0xF, 0xF, false))
#define RDLANE(v, l) I2F(__builtin_amdgcn_readlane(F2I(v), (l)))

__device__ __forceinline__ float fast_sigmoid(float x) {
  float e = __expf(-x);
  return __fdividef(1.0f, 1.0f + e);
}

__device__ __forceinline__ unsigned short f2bf(float f) {
  unsigned int u = __float_as_uint(f);
  u += 0x7FFFu + ((u >> 16) & 1u);   // round-to-nearest-even
  return (unsigned short)(u >> 16);
}
__device__ __forceinline__ float bf2f(unsigned short s) {
  return __uint_as_float(((unsigned int)s) << 16);
}

// ---------------- Kernel 1: input projection ----------------
// grid = 4096 blocks x 256 threads (4 waves). Block handles 64 rows.
// lane = permuted output column; wave wid handles rows wid*16 .. wid*16+15.
__global__ __launch_bounds__(256) void k1_xproj(
    const float* __restrict__ x, const float* __restrict__ Wih,
    const float* __restrict__ bih, const float* __restrict__ bhh,
    unsigned short* __restrict__ xproj)
{
  __shared__ float xs[64 * 200];                  // 51.2 KB
  const int tid  = threadIdx.x;
  const int lane = tid & 63;
  const int wid  = tid >> 6;
  const long row0 = (long)blockIdx.x * 64;

  // ---- stage x[row0 .. row0+64) -> LDS (contiguous 51200 B, coalesced) ----
  const float4* xsrc = reinterpret_cast<const float4*>(x + row0 * 200);
  float4* xdst = reinterpret_cast<float4*>(xs);
#pragma unroll
  for (int it = 0; it < 12; ++it) xdst[it * 256 + tid] = xsrc[it * 256 + tid];
  if (tid < 128) xdst[12 * 256 + tid] = xsrc[12 * 256 + tid];
  __syncthreads();

  // ---- compute: lane = col, 16 rows per wave ----
  const int r = ((lane & 3) << 4) | (lane >> 2);  // gate row in [0,64)
  const float bias = bih[r] + bhh[r];
  const float* wrow = Wih + r * 200;
  const int rbase = wid * 16;

  float acc[16];
#pragma unroll
  for (int i = 0; i < 16; ++i) acc[i] = bias;

#pragma unroll 1
  for (int c = 0; c < 6; ++c) {                   // k = 0..191 in chunks of 32
    float4 w[8];
#pragma unroll
    for (int q = 0; q < 8; ++q)
      w[q] = *reinterpret_cast<const float4*>(wrow + c * 32 + q * 4);
#pragma unroll
    for (int i = 0; i < 16; ++i) {
      const float4* xr = reinterpret_cast<const float4*>(xs + (rbase + i) * 200 + c * 32);
      float s0 = 0.f, s1 = 0.f, s2 = 0.f, s3 = 0.f;
#pragma unroll
      for (int q = 0; q < 8; ++q) {
        float4 xa = xr[q];                        // LDS broadcast (uniform addr)
        s0 = fmaf(xa.x, w[q].x, s0);
        s1 = fmaf(xa.y, w[q].y, s1);
        s2 = fmaf(xa.z, w[q].z, s2);
        s3 = fmaf(xa.w, w[q].w, s3);
      }
      acc[i] += (s0 + s1) + (s2 + s3);
    }
  }
  { // tail k = 192..199
    float4 w0 = *reinterpret_cast<const float4*>(wrow + 192);
    float4 w1 = *reinterpret_cast<const float4*>(wrow + 196);
#pragma unroll
    for (int i = 0; i < 16; ++i) {
      const float4* xr = reinterpret_cast<const float4*>(xs + (rbase + i) * 200 + 192);
      float4 a0 = xr[0], a1 = xr[1];
      acc[i] += a0.x * w0.x + a0.y * w0.y + a0.z * w0.z + a0.w * w0.w
              + a1.x * w1.x + a1.y * w1.y + a1.z * w1.z + a1.w * w1.w;
    }
  }

  // ---- store bf16, coalesced (64 cols = 128B per row) ----
  unsigned short* xp = xproj + row0 * 64 + lane;
#pragma unroll
  for (int i = 0; i < 16; ++i)
    xp[(size_t)(rbase + i) * 64] = f2bf(acc[i]);
}

// ---------------- Kernel 2: fused LSTM scan + head ----------------
// grid = 256 blocks x 64 threads; one wave per batch row.
// lane: j = lane>>2 (hidden unit), g = lane&3 (gate: 0=i,1=f,2=g,3=o).
__global__ __launch_bounds__(64, 1) void k2_scan(
    const unsigned short* __restrict__ xproj,
    const float* __restrict__ h0, const float* __restrict__ c0,
    const float* __restrict__ Whh,
    const float* __restrict__ W1, const float* __restrict__ b1,
    const float* __restrict__ W2, const float* __restrict__ b2,
    float* __restrict__ out)
{
  const int b = blockIdx.x;
  const int lane = threadIdx.x;
  const int g = lane & 3;
  const int j = lane >> 2;
  const int r = (g << 4) | j;

  float whh[16];
#pragma unroll
  for (int q = 0; q < 4; ++q) {
    float4 w = *reinterpret_cast<const float4*>(Whh + r * 16 + q * 4);
    whh[q * 4 + 0] = w.x; whh[q * 4 + 1] = w.y;
    whh[q * 4 + 2] = w.z; whh[q * 4 + 3] = w.w;
  }
  float w1row[16];
#pragma unroll
  for (int k = 0; k < 16; ++k) w1row[k] = W1[j * 16 + k];
  const float w2j = W2[j];
  const float b1j = b1[j];
  const float b2s = b2[0];

  float c = c0[b * 16 + j];
  float hmine = h0[b * 16 + j];
  float hs[16];                    // wave-uniform h -> SGPRs
#pragma unroll
  for (int k = 0; k < 16; ++k) hs[k] = RDLANE(hmine, 4 * k);

  const float mfac = (g == 2) ? -2.f : -1.f;
  const float pfac = (g == 2) ?  2.f :  1.f;
  const float qfac = (g == 2) ? -1.f :  0.f;

  const unsigned short* xp = xproj + (size_t)b * (T_LEN * 64) + lane;
  float buf[8];                    // 8-deep prefetch, converted at load time
#pragma unroll
  for (int u = 0; u < 8; ++u) buf[u] = bf2f(xp[(size_t)u * 64]);

  float accs = 0.f;

  for (int tb = 0; tb < T_LEN; tb += 8) {
#pragma unroll
    for (int u = 0; u < 8; ++u) {
      const float gin = buf[u];
      int tn = tb + 8 + u;
      tn = (tn < T_LEN) ? tn : (T_LEN - 8 + u);
      buf[u] = bf2f(xp[(size_t)tn * 64]);

      // recurrent dot, tree-structured: 4 chains of 4 + 2-level combine
      float s0 = fmaf(whh[0],  hs[0],  gin);
      s0 = fmaf(whh[1],  hs[1],  s0);
      s0 = fmaf(whh[2],  hs[2],  s0);
      s0 = fmaf(whh[3],  hs[3],  s0);
      float s1 = whh[4] * hs[4];
      s1 = fmaf(whh[5],  hs[5],  s1);
      s1 = fmaf(whh[6],  hs[6],  s1);
      s1 = fmaf(whh[7],  hs[7],  s1);
      float s2 = whh[8] * hs[8];
      s2 = fmaf(whh[9],  hs[9],  s2);
      s2 = fmaf(whh[10], hs[10], s2);
      s2 = fmaf(whh[11], hs[11], s2);
      float s3 = whh[12] * hs[12];
      s3 = fmaf(whh[13], hs[13], s3);
      s3 = fmaf(whh[14], hs[14], s3);
      s3 = fmaf(whh[15], hs[15], s3);
      float pre = (s0 + s1) + (s2 + s3);

      // unified sigmoid/tanh
      float e = __expf(mfac * pre);
      float z = __fdividef(1.f, 1.f + e);
      float y = fmaf(pfac, z, qfac);

      // broadcast 4 gate activations within each quad (DPP)
      float ai = DPPF(y, 0x00);
      float af = DPPF(y, 0x55);
      float ag = DPPF(y, 0xAA);
      float ao = DPPF(y, 0xFF);

      c = fmaf(af, c, ai * ag);
      float e2 = __expf(-2.f * c);
      float th = fmaf(2.f, __fdividef(1.f, 1.f + e2), -1.f);
      float h = ao * th;

#pragma unroll
      for (int k = 0; k < 16; ++k) hs[k] = RDLANE(h, 4 * k);

      // ---- head (off critical path) ----
      float p0 = fmaf(w1row[0],  hs[0],  b1j);
      p0 = fmaf(w1row[1],  hs[1],  p0);
      p0 = fmaf(w1row[2],  hs[2],  p0);
      p0 = fmaf(w1row[3],  hs[3],  p0);
      float p1 = w1row[4] * hs[4];
      p1 = fmaf(w1row[5],  hs[5],  p1);
      p1 = fmaf(w1row[6],  hs[6],  p1);
      p1 = fmaf(w1row[7],  hs[7],  p1);
      float p2 = w1row[8] * hs[8];
      p2 = fmaf(w1row[9],  hs[9],  p2);
      p2 = fmaf(w1row[10], hs[10], p2);
      p2 = fmaf(w1row[11], hs[11], p2);
      float p3 = w1row[12] * hs[12];
      p3 = fmaf(w1row[13], hs[13], p3);
      p3 = fmaf(w1row[14], hs[14], p3);
      p3 = fmaf(w1row[15], hs[15], p3);
      float p = (p0 + p1) + (p2 + p3);
      p = fmaxf(p, 0.f);
      float pl = p * w2j;

      // sum the 16 distinct j's (quad-uniform values)
      float v = pl;
      v = v + DPPF(v, 0x124);     // row_ror:4
      v = v + DPPF(v, 0x128);     // row_ror:8
      v = v + I2F(__builtin_amdgcn_ds_swizzle(F2I(v), 0x401F));  // xor 16
      v = v + __shfl_xor(v, 32, 64);                              // xor 32

      accs += fast_sigmoid(b2s + v);
    }
  }

  if (lane == 0) out[b] = accs * (1.0f / T_LEN);
}

// ---------------- launcher ----------------
extern "C" void kernel_launch(void* const* d_in, const int* in_sizes, int n_in,
                              void* d_out, int out_size, void* d_ws, size_t ws_size,
                              hipStream_t stream) {
  const float* x   = (const float*)d_in[0];
  const float* h0  = (const float*)d_in[1];
  const float* c0  = (const float*)d_in[2];
  const float* Wih = (const float*)d_in[3];
  const float* Whh = (const float*)d_in[4];
  const float* bih = (const float*)d_in[5];
  const float* bhh = (const float*)d_in[6];
  const float* W1  = (const float*)d_in[7];
  const float* b1  = (const float*)d_in[8];
  const float* W2  = (const float*)d_in[9];
  const float* b2  = (const float*)d_in[10];

  unsigned short* xproj = (unsigned short*)d_ws;  // 256*1024*64*2 = 32 MiB

  hipLaunchKernelGGL(k1_xproj, dim3(4096), dim3(256), 0, stream,
                     x, Wih, bih, bhh, xproj);
  hipLaunchKernelGGL(k2_scan, dim3(NB), dim3(64), 0, stream,
                     xproj, h0, c0, Whh, W1, b1, W2, b2, (float*)d_out);
}

// Round 3
// 352.032 us; speedup vs baseline: 1.5088x; 1.3925x over previous
//
#include <hip/hip_runtime.h>

// LSTMDiscriminator: B=256, T=1024, I=200, H=16
// K1: x_proj = x @ W_ih^T + b_ih + b_hh  (bf16, permuted cols for K2)
// K2: LSTM scan only; xproj double-buffered in LDS via global_load_lds;
//     log2e folded into weights; h stored to ws as bf16 per step.
// K3: head relu(h@W1^T+b1)@W2^T+b2 -> sigmoid -> mean over T.

#define T_LEN 1024
#define NB    256
#define CHUNK 128
#define NCH   (T_LEN / CHUNK)

#define F2I(x) __float_as_int(x)
#define I2F(x) __int_as_float(x)
#define DPPF(v, ctrl) I2F(__builtin_amdgcn_update_dpp(F2I(v), F2I(v), (ctrl), 0xF, 0xF, false))
#define RDLANE(v, l) I2F(__builtin_amdgcn_readlane(F2I(v), (l)))

#define LOG2E 1.442695040888963f

#if __has_builtin(__builtin_amdgcn_exp2f)
__device__ __forceinline__ float fexp2(float x) { return __builtin_amdgcn_exp2f(x); }
#else
__device__ __forceinline__ float fexp2(float x) { return exp2f(x); }
#endif
#if __has_builtin(__builtin_amdgcn_rcpf)
__device__ __forceinline__ float frcp(float x) { return __builtin_amdgcn_rcpf(x); }
#else
__device__ __forceinline__ float frcp(float x) { return __fdividef(1.f, x); }
#endif

__device__ __forceinline__ unsigned short f2bf(float f) {
  unsigned int u = __float_as_uint(f);
  u += 0x7FFFu + ((u >> 16) & 1u);
  return (unsigned short)(u >> 16);
}
__device__ __forceinline__ float bf2f(unsigned short s) {
  return __uint_as_float(((unsigned int)s) << 16);
}

// ---------------- Kernel 1: input projection ----------------
// grid = 4096 x 512 (8 waves). Block: 64 rows; wave wid: rows wid*8..wid*8+7.
__global__ __launch_bounds__(512) void k1_xproj(
    const float* __restrict__ x, const float* __restrict__ Wih,
    const float* __restrict__ bih, const float* __restrict__ bhh,
    unsigned short* __restrict__ xproj)
{
  __shared__ float xs[64 * 200];                  // 51.2 KB
  const int tid  = threadIdx.x;
  const int lane = tid & 63;
  const int wid  = tid >> 6;
  const long row0 = (long)blockIdx.x * 64;

  // stage x tile -> LDS (12800 floats = 3200 float4, coalesced)
  const float4* xsrc = reinterpret_cast<const float4*>(x + row0 * 200);
  float4* xdst = reinterpret_cast<float4*>(xs);
#pragma unroll
  for (int it = 0; it < 6; ++it) xdst[it * 512 + tid] = xsrc[it * 512 + tid];
  if (tid < 128) xdst[6 * 512 + tid] = xsrc[6 * 512 + tid];
  __syncthreads();

  const int r = ((lane & 3) << 4) | (lane >> 2);  // gate row in [0,64)
  const float bias = bih[r] + bhh[r];
  const float* wrow = Wih + r * 200;
  const int rbase = wid * 8;

  float acc[8];
#pragma unroll
  for (int i = 0; i < 8; ++i) acc[i] = bias;

#pragma unroll 1
  for (int c = 0; c < 6; ++c) {                   // k = 0..191 in chunks of 32
    float4 w[8];
#pragma unroll
    for (int q = 0; q < 8; ++q)
      w[q] = *reinterpret_cast<const float4*>(wrow + c * 32 + q * 4);
#pragma unroll
    for (int i = 0; i < 8; ++i) {
      const float4* xr = reinterpret_cast<const float4*>(xs + (rbase + i) * 200 + c * 32);
      float s0 = 0.f, s1 = 0.f, s2 = 0.f, s3 = 0.f;
#pragma unroll
      for (int q = 0; q < 8; ++q) {
        float4 xa = xr[q];                        // LDS broadcast
        s0 = fmaf(xa.x, w[q].x, s0);
        s1 = fmaf(xa.y, w[q].y, s1);
        s2 = fmaf(xa.z, w[q].z, s2);
        s3 = fmaf(xa.w, w[q].w, s3);
      }
      acc[i] += (s0 + s1) + (s2 + s3);
    }
  }
  { // tail k = 192..199
    float4 w0 = *reinterpret_cast<const float4*>(wrow + 192);
    float4 w1 = *reinterpret_cast<const float4*>(wrow + 196);
#pragma unroll
    for (int i = 0; i < 8; ++i) {
      const float4* xr = reinterpret_cast<const float4*>(xs + (rbase + i) * 200 + 192);
      float4 a0 = xr[0], a1 = xr[1];
      acc[i] += a0.x * w0.x + a0.y * w0.y + a0.z * w0.z + a0.w * w0.w
              + a1.x * w1.x + a1.y * w1.y + a1.z * w1.z + a1.w * w1.w;
    }
  }

  unsigned short* xp = xproj + row0 * 64 + lane;
#pragma unroll
  for (int i = 0; i < 8; ++i)
    xp[(size_t)(rbase + i) * 64] = f2bf(acc[i]);
}

// ---------------- Kernel 2: LSTM scan ----------------
// grid = 256 x 64; one wave per batch row.
// lane: j = lane>>2, g = lane&3 (0=i,1=f,2=g,3=o).
__device__ __forceinline__ void stage_chunk(const unsigned short* g,
                                            unsigned short* l, int lane) {
#pragma unroll
  for (int it = 0; it < 16; ++it) {   // 16 x 1KB = 16KB (128 steps x 128B)
    __builtin_amdgcn_global_load_lds(
        (const __attribute__((address_space(1))) unsigned int*)(g + it * 512 + lane * 8),
        (__attribute__((address_space(3))) unsigned int*)(l + it * 512),
        16, 0, 0);
  }
}

__global__ __launch_bounds__(64, 1) void k2_scan(
    const unsigned short* __restrict__ xproj,
    const float* __restrict__ h0, const float* __restrict__ c0,
    const float* __restrict__ Whh,
    unsigned short* __restrict__ hst)
{
  __shared__ unsigned short xs[2][CHUNK * 64];    // 2 x 16KB
  const int b = blockIdx.x;
  const int lane = threadIdx.x;
  const int g = lane & 3;
  const int j = lane >> 2;
  const int r = (g << 4) | j;

  const unsigned short* gx = xproj + (size_t)b * (T_LEN * 64);
  stage_chunk(gx, xs[0], lane);                   // chunk 0 in flight

  // per-lane constants; fold sfac = mfac*log2e into weights and gin
  const float sfac = (g == 2) ? (-2.f * LOG2E) : (-LOG2E);
  const float pfac = (g == 2) ?  2.f :  1.f;
  const float qfac = (g == 2) ? -1.f :  0.f;

  float whh[16];
#pragma unroll
  for (int q = 0; q < 4; ++q) {
    float4 w = *reinterpret_cast<const float4*>(Whh + r * 16 + q * 4);
    whh[q * 4 + 0] = w.x * sfac; whh[q * 4 + 1] = w.y * sfac;
    whh[q * 4 + 2] = w.z * sfac; whh[q * 4 + 3] = w.w * sfac;
  }

  float c = c0[b * 16 + j];
  float hmine = h0[b * 16 + j];
  float hs[16];
#pragma unroll
  for (int k = 0; k < 16; ++k) hs[k] = RDLANE(hmine, 4 * k);

  unsigned short* hq = hst + (size_t)b * (T_LEN * 16) + j;
  const bool dostore = (g == 0);

  __syncthreads();                                // chunk 0 staged

  float buf[8];
#pragma unroll
  for (int u = 0; u < 8; ++u) buf[u] = bf2f(xs[0][u * 64 + lane]) * sfac;

  for (int ch = 0; ch < NCH; ++ch) {
    const unsigned short* xcur = xs[ch & 1];
    if (ch + 1 < NCH) stage_chunk(gx + (ch + 1) * (CHUNK * 64),
                                  (unsigned short*)xs[(ch + 1) & 1], lane);

    for (int ts = 0; ts < CHUNK; ts += 8) {
#pragma unroll
      for (int u = 0; u < 8; ++u) {
        const float gin = buf[u];
        int tn = ts + 8 + u;
        tn = (tn < CHUNK) ? tn : (CHUNK - 1);     // dummy reload at chunk tail
        buf[u] = bf2f(xcur[tn * 64 + lane]) * sfac;

        // pre' = sfac * (gin_raw + Whh h)  (already folded)
        float s0 = fmaf(whh[0],  hs[0],  gin);
        s0 = fmaf(whh[1],  hs[1],  s0);
        s0 = fmaf(whh[2],  hs[2],  s0);
        s0 = fmaf(whh[3],  hs[3],  s0);
        float s1 = whh[4] * hs[4];
        s1 = fmaf(whh[5],  hs[5],  s1);
        s1 = fmaf(whh[6],  hs[6],  s1);
        s1 = fmaf(whh[7],  hs[7],  s1);
        float s2 = whh[8] * hs[8];
        s2 = fmaf(whh[9],  hs[9],  s2);
        s2 = fmaf(whh[10], hs[10], s2);
        s2 = fmaf(whh[11], hs[11], s2);
        float s3 = whh[12] * hs[12];
        s3 = fmaf(whh[13], hs[13], s3);
        s3 = fmaf(whh[14], hs[14], s3);
        s3 = fmaf(whh[15], hs[15], s3);
        float pre = (s0 + s1) + (s2 + s3);

        float e = fexp2(pre);                     // exp(mfac * pre_raw)
        float z = frcp(1.f + e);
        float y = fmaf(pfac, z, qfac);            // sigmoid or tanh

        float ai = DPPF(y, 0x00);
        float af = DPPF(y, 0x55);
        float ag = DPPF(y, 0xAA);
        float ao = DPPF(y, 0xFF);

        c = fmaf(af, c, ai * ag);
        float e2 = fexp2((2.f * LOG2E) * c);      // e^{2c}
        float th = fmaf(-2.f, frcp(1.f + e2), 1.f); // tanh(c)
        float h = ao * th;

#pragma unroll
        for (int k = 0; k < 16; ++k) hs[k] = RDLANE(h, 4 * k);

        if (dostore)
          hq[(size_t)(ch * CHUNK + ts + u) * 16] = f2bf(h);
      }
    }

    __syncthreads();                              // next chunk staged; reads drained
    if (ch + 1 < NCH) {
      const unsigned short* xn = xs[(ch + 1) & 1];
#pragma unroll
      for (int u = 0; u < 8; ++u) buf[u] = bf2f(xn[u * 64 + lane]) * sfac;
    }
  }
}

// ---------------- Kernel 3: head + mean ----------------
// grid = 256 (one per b) x 256 threads; each thread 4 timesteps.
__global__ __launch_bounds__(256) void k3_head(
    const unsigned short* __restrict__ hst,
    const float* __restrict__ W1, const float* __restrict__ b1,
    const float* __restrict__ W2, const float* __restrict__ b2,
    float* __restrict__ out)
{
  __shared__ float ws1[256];
  __shared__ float wsb1[16], wsw2[16];
  __shared__ float red[256];
  const int tid = threadIdx.x;
  const int b = blockIdx.x;

  ws1[tid] = W1[tid];
  if (tid < 16) { wsb1[tid] = b1[tid]; wsw2[tid] = W2[tid]; }
  __syncthreads();
  const float b2s = b2[0];

  float acc = 0.f;
#pragma unroll
  for (int it = 0; it < 4; ++it) {
    const int t = it * 256 + tid;
    const uint4* hp = reinterpret_cast<const uint4*>(hst + ((size_t)b * T_LEN + t) * 16);
    uint4 ha = hp[0], hb = hp[1];
    float h[16];
    h[0]  = bf2f((unsigned short)(ha.x & 0xffff)); h[1]  = bf2f((unsigned short)(ha.x >> 16));
    h[2]  = bf2f((unsigned short)(ha.y & 0xffff)); h[3]  = bf2f((unsigned short)(ha.y >> 16));
    h[4]  = bf2f((unsigned short)(ha.z & 0xffff)); h[5]  = bf2f((unsigned short)(ha.z >> 16));
    h[6]  = bf2f((unsigned short)(ha.w & 0xffff)); h[7]  = bf2f((unsigned short)(ha.w >> 16));
    h[8]  = bf2f((unsigned short)(hb.x & 0xffff)); h[9]  = bf2f((unsigned short)(hb.x >> 16));
    h[10] = bf2f((unsigned short)(hb.y & 0xffff)); h[11] = bf2f((unsigned short)(hb.y >> 16));
    h[12] = bf2f((unsigned short)(hb.z & 0xffff)); h[13] = bf2f((unsigned short)(hb.z >> 16));
    h[14] = bf2f((unsigned short)(hb.w & 0xffff)); h[15] = bf2f((unsigned short)(hb.w >> 16));

    float s = b2s;
#pragma unroll
    for (int jj = 0; jj < 16; ++jj) {
      float p = wsb1[jj];
#pragma unroll
      for (int k = 0; k < 16; ++k) p = fmaf(ws1[jj * 16 + k], h[k], p);
      p = fmaxf(p, 0.f);
      s = fmaf(wsw2[jj], p, s);
    }
    float e = fexp2(-LOG2E * s);
    acc += frcp(1.f + e);
  }

  red[tid] = acc;
  __syncthreads();
  if (tid < 128) red[tid] += red[tid + 128];
  __syncthreads();
  if (tid < 64) {
    float v = red[tid] + red[tid + 64];
    v += __shfl_xor(v, 32, 64);
    v += __shfl_xor(v, 16, 64);
    v += __shfl_xor(v, 8, 64);
    v += __shfl_xor(v, 4, 64);
    v += __shfl_xor(v, 2, 64);
    v += __shfl_xor(v, 1, 64);
    if (tid == 0) out[b] = v * (1.f / T_LEN);
  }
}

// ---------------- launcher ----------------
extern "C" void kernel_launch(void* const* d_in, const int* in_sizes, int n_in,
                              void* d_out, int out_size, void* d_ws, size_t ws_size,
                              hipStream_t stream) {
  const float* x   = (const float*)d_in[0];
  const float* h0  = (const float*)d_in[1];
  const float* c0  = (const float*)d_in[2];
  const float* Wih = (const float*)d_in[3];
  const float* Whh = (const float*)d_in[4];
  const float* bih = (const float*)d_in[5];
  const float* bhh = (const float*)d_in[6];
  const float* W1  = (const float*)d_in[7];
  const float* b1  = (const float*)d_in[8];
  const float* W2  = (const float*)d_in[9];
  const float* b2  = (const float*)d_in[10];

  unsigned short* xproj = (unsigned short*)d_ws;                 // 32 MiB
  unsigned short* hst   = (unsigned short*)((char*)d_ws + (size_t)32 * 1024 * 1024); // 8 MiB

  hipLaunchKernelGGL(k1_xproj, dim3(4096), dim3(512), 0, stream,
                     x, Wih, bih, bhh, xproj);
  hipLaunchKernelGGL(k2_scan, dim3(NB), dim3(64), 0, stream,
                     xproj, h0, c0, Whh, hst);
  hipLaunchKernelGGL(k3_head, dim3(NB), dim3(256), 0, stream,
                     hst, W1, b1, W2, b2, (float*)d_out);
}

// Round 4
// 200.683 us; speedup vs baseline: 2.6467x; 1.7542x over previous
//
#include <hip/hip_runtime.h>

// LSTMDiscriminator: B=256, T=1024, I=200, H=16
// K0: prepack W_ih (permuted cols, bf16, fragment-linear) + fused bias -> ws
// K1: x_proj = x @ W_ih^T + bias via MFMA 16x16x32 bf16 (M=262144,N=64,K=224pad)
// K2: LSTM scan; xproj double-buffered in LDS via global_load_lds
// K3: head relu(h@W1^T+b1)@W2^T+b2 -> sigmoid -> mean over T

#define T_LEN 1024
#define NB    256
#define CHUNK 128
#define NCH   (T_LEN / CHUNK)

#define F2I(x) __float_as_int(x)
#define I2F(x) __int_as_float(x)
#define DPPF(v, ctrl) I2F(__builtin_amdgcn_update_dpp(F2I(v), F2I(v), (ctrl), 0xF, 0xF, false))
#define RDLANE(v, l) I2F(__builtin_amdgcn_readlane(F2I(v), (l)))

#define LOG2E 1.442695040888963f

typedef __bf16 bf16_t;
typedef bf16_t bf16x8 __attribute__((ext_vector_type(8)));
typedef float f32x4 __attribute__((ext_vector_type(4)));

#if __has_builtin(__builtin_amdgcn_exp2f)
__device__ __forceinline__ float fexp2(float x) { return __builtin_amdgcn_exp2f(x); }
#else
__device__ __forceinline__ float fexp2(float x) { return exp2f(x); }
#endif
#if __has_builtin(__builtin_amdgcn_rcpf)
__device__ __forceinline__ float frcp(float x) { return __builtin_amdgcn_rcpf(x); }
#else
__device__ __forceinline__ float frcp(float x) { return __fdividef(1.f, x); }
#endif

__device__ __forceinline__ unsigned short f2bf(float f) {
  unsigned int u = __float_as_uint(f);
  u += 0x7FFFu + ((u >> 16) & 1u);
  return (unsigned short)(u >> 16);
}
__device__ __forceinline__ float bf2f(unsigned short s) {
  return __uint_as_float(((unsigned int)s) << 16);
}

// ---------------- Kernel 0: prepack W (bf16, fragment-linear) + bias ----------------
// B-frag chunk layout: chunk idx = (f*7 + s)*64 + L holds B[k = s*32+(L>>4)*8+e][col = f*16+(L&15)]
// where col c maps to gate row r = ((c&3)<<4)|(c>>2). k >= 200 zero-padded.
__global__ __launch_bounds__(256) void k0_prep(
    const float* __restrict__ Wih, const float* __restrict__ bih,
    const float* __restrict__ bhh, bf16x8* __restrict__ wB,
    float* __restrict__ biasPerm)
{
  const int idx = blockIdx.x * 256 + threadIdx.x;   // 0..1791
  if (idx < 4 * 7 * 64) {
    const int f = idx / 448;
    const int rem = idx % 448;
    const int s = rem / 64;
    const int L = rem % 64;
    const int col = f * 16 + (L & 15);
    const int r = ((col & 3) << 4) | (col >> 2);
    const int k0 = s * 32 + (L >> 4) * 8;
    bf16x8 v;
#pragma unroll
    for (int e = 0; e < 8; ++e) {
      const int k = k0 + e;
      const float w = (k < 200) ? Wih[r * 200 + k] : 0.f;
      v[e] = (bf16_t)w;
    }
    wB[idx] = v;
  }
  if (blockIdx.x == 0 && threadIdx.x < 64) {
    const int c = threadIdx.x;
    const int r = ((c & 3) << 4) | (c >> 2);
    biasPerm[c] = bih[r] + bhh[r];
  }
}

// ---------------- Kernel 1: x projection via MFMA ----------------
// grid = 4096 x 256 (4 waves). Block: 64 rows x 64 cols, K=224 (7 steps of 32).
// Wave w owns rows w*16..w*16+15. Fragment-linear LDS: all frag I/O = base + lane*16.
__global__ __launch_bounds__(256) void k1_xproj(
    const float* __restrict__ x, const bf16x8* __restrict__ wB,
    const float* __restrict__ biasPerm, unsigned short* __restrict__ xproj)
{
  __shared__ bf16x8 As[4 * 7 * 64];   // 28672 B
  __shared__ bf16x8 Bs[4 * 7 * 64];   // 28672 B

  const int tid = threadIdx.x;
  const int L = tid & 63;
  const int w = tid >> 6;
  const long row0 = (long)blockIdx.x * 64;

  // ---- B: async DMA 28 KB global -> LDS (wave 0 issues) ----
  if (w == 0) {
    const unsigned short* src = (const unsigned short*)wB;
    unsigned short* dst = (unsigned short*)Bs;
#pragma unroll
    for (int it = 0; it < 28; ++it) {
      __builtin_amdgcn_global_load_lds(
          (const __attribute__((address_space(1))) unsigned int*)(src + it * 512 + L * 8),
          (__attribute__((address_space(3))) unsigned int*)(dst + it * 512),
          16, 0, 0);
    }
  }

  // ---- A: load own row chunk, cvt bf16, write fragment-linear ----
  const float* xr = x + (row0 + w * 16 + (L & 15)) * 200;
  const int kg = (L >> 4) * 8;
#pragma unroll
  for (int s = 0; s < 7; ++s) {
    const int k0 = s * 32 + kg;
    bf16x8 v;
    if (k0 < 200) {                    // k0 in {0..192}; 192 -> reads 192..199 exactly
      float4 a = *reinterpret_cast<const float4*>(xr + k0);
      float4 b = *reinterpret_cast<const float4*>(xr + k0 + 4);
      v[0] = (bf16_t)a.x; v[1] = (bf16_t)a.y; v[2] = (bf16_t)a.z; v[3] = (bf16_t)a.w;
      v[4] = (bf16_t)b.x; v[5] = (bf16_t)b.y; v[6] = (bf16_t)b.z; v[7] = (bf16_t)b.w;
    } else {
      v[0] = (bf16_t)0.f; v[1] = (bf16_t)0.f; v[2] = (bf16_t)0.f; v[3] = (bf16_t)0.f;
      v[4] = (bf16_t)0.f; v[5] = (bf16_t)0.f; v[6] = (bf16_t)0.f; v[7] = (bf16_t)0.f;
    }
    As[(w * 7 + s) * 64 + L] = v;      // ds_write_b128, conflict-free
  }

  __syncthreads();                     // A staged + B DMA drained

  // ---- MFMA: 7 K-steps x 4 col-frags ----
  f32x4 acc0 = {0.f, 0.f, 0.f, 0.f};
  f32x4 acc1 = {0.f, 0.f, 0.f, 0.f};
  f32x4 acc2 = {0.f, 0.f, 0.f, 0.f};
  f32x4 acc3 = {0.f, 0.f, 0.f, 0.f};
#pragma unroll
  for (int s = 0; s < 7; ++s) {
    const bf16x8 a = As[(w * 7 + s) * 64 + L];
    acc0 = __builtin_amdgcn_mfma_f32_16x16x32_bf16(a, Bs[(0 * 7 + s) * 64 + L], acc0, 0, 0, 0);
    acc1 = __builtin_amdgcn_mfma_f32_16x16x32_bf16(a, Bs[(1 * 7 + s) * 64 + L], acc1, 0, 0, 0);
    acc2 = __builtin_amdgcn_mfma_f32_16x16x32_bf16(a, Bs[(2 * 7 + s) * 64 + L], acc2, 0, 0, 0);
    acc3 = __builtin_amdgcn_mfma_f32_16x16x32_bf16(a, Bs[(3 * 7 + s) * 64 + L], acc3, 0, 0, 0);
  }

  // ---- epilogue: + bias, store bf16 (C/D: col=lane&15, row=(lane>>4)*4+q) ----
  const int cb = L & 15;
  const long rbase = row0 + w * 16 + ((L >> 4) << 2);
  __bf16* xo = (__bf16*)xproj;
  const float bv0 = biasPerm[0 * 16 + cb];
  const float bv1 = biasPerm[1 * 16 + cb];
  const float bv2 = biasPerm[2 * 16 + cb];
  const float bv3 = biasPerm[3 * 16 + cb];
#pragma unroll
  for (int q = 0; q < 4; ++q) {
    __bf16* row = xo + (rbase + q) * 64;
    row[ 0 + cb] = (bf16_t)(acc0[q] + bv0);
    row[16 + cb] = (bf16_t)(acc1[q] + bv1);
    row[32 + cb] = (bf16_t)(acc2[q] + bv2);
    row[48 + cb] = (bf16_t)(acc3[q] + bv3);
  }
}

// ---------------- Kernel 2: LSTM scan ----------------
__device__ __forceinline__ void stage_chunk(const unsigned short* g,
                                            unsigned short* l, int lane) {
#pragma unroll
  for (int it = 0; it < 16; ++it) {   // 16 x 1KB = 16KB (128 steps x 128B)
    __builtin_amdgcn_global_load_lds(
        (const __attribute__((address_space(1))) unsigned int*)(g + it * 512 + lane * 8),
        (__attribute__((address_space(3))) unsigned int*)(l + it * 512),
        16, 0, 0);
  }
}

__global__ __launch_bounds__(64, 1) void k2_scan(
    const unsigned short* __restrict__ xproj,
    const float* __restrict__ h0, const float* __restrict__ c0,
    const float* __restrict__ Whh,
    unsigned short* __restrict__ hst)
{
  __shared__ unsigned short xs[2][CHUNK * 64];    // 2 x 16KB
  const int b = blockIdx.x;
  const int lane = threadIdx.x;
  const int g = lane & 3;
  const int j = lane >> 2;
  const int r = (g << 4) | j;

  const unsigned short* gx = xproj + (size_t)b * (T_LEN * 64);
  stage_chunk(gx, xs[0], lane);                   // chunk 0 in flight

  const float sfac = (g == 2) ? (-2.f * LOG2E) : (-LOG2E);
  const float pfac = (g == 2) ?  2.f :  1.f;
  const float qfac = (g == 2) ? -1.f :  0.f;

  float whh[16];
#pragma unroll
  for (int q = 0; q < 4; ++q) {
    float4 w = *reinterpret_cast<const float4*>(Whh + r * 16 + q * 4);
    whh[q * 4 + 0] = w.x * sfac; whh[q * 4 + 1] = w.y * sfac;
    whh[q * 4 + 2] = w.z * sfac; whh[q * 4 + 3] = w.w * sfac;
  }

  float c = c0[b * 16 + j];
  float hmine = h0[b * 16 + j];
  float hs[16];
#pragma unroll
  for (int k = 0; k < 16; ++k) hs[k] = RDLANE(hmine, 4 * k);

  unsigned short* hq = hst + (size_t)b * (T_LEN * 16) + j;
  const bool dostore = (g == 0);

  __syncthreads();                                // chunk 0 staged

  float buf[8];
#pragma unroll
  for (int u = 0; u < 8; ++u) buf[u] = bf2f(xs[0][u * 64 + lane]) * sfac;

  for (int ch = 0; ch < NCH; ++ch) {
    const unsigned short* xcur = xs[ch & 1];
    if (ch + 1 < NCH) stage_chunk(gx + (ch + 1) * (CHUNK * 64),
                                  (unsigned short*)xs[(ch + 1) & 1], lane);

    for (int ts = 0; ts < CHUNK; ts += 8) {
#pragma unroll
      for (int u = 0; u < 8; ++u) {
        const float gin = buf[u];
        int tn = ts + 8 + u;
        tn = (tn < CHUNK) ? tn : (CHUNK - 1);
        buf[u] = bf2f(xcur[tn * 64 + lane]) * sfac;

        float s0 = fmaf(whh[0],  hs[0],  gin);
        s0 = fmaf(whh[1],  hs[1],  s0);
        s0 = fmaf(whh[2],  hs[2],  s0);
        s0 = fmaf(whh[3],  hs[3],  s0);
        float s1 = whh[4] * hs[4];
        s1 = fmaf(whh[5],  hs[5],  s1);
        s1 = fmaf(whh[6],  hs[6],  s1);
        s1 = fmaf(whh[7],  hs[7],  s1);
        float s2 = whh[8] * hs[8];
        s2 = fmaf(whh[9],  hs[9],  s2);
        s2 = fmaf(whh[10], hs[10], s2);
        s2 = fmaf(whh[11], hs[11], s2);
        float s3 = whh[12] * hs[12];
        s3 = fmaf(whh[13], hs[13], s3);
        s3 = fmaf(whh[14], hs[14], s3);
        s3 = fmaf(whh[15], hs[15], s3);
        float pre = (s0 + s1) + (s2 + s3);

        float e = fexp2(pre);
        float z = frcp(1.f + e);
        float y = fmaf(pfac, z, qfac);

        float ai = DPPF(y, 0x00);
        float af = DPPF(y, 0x55);
        float ag = DPPF(y, 0xAA);
        float ao = DPPF(y, 0xFF);

        c = fmaf(af, c, ai * ag);
        float e2 = fexp2((2.f * LOG2E) * c);
        float th = fmaf(-2.f, frcp(1.f + e2), 1.f);
        float h = ao * th;

#pragma unroll
        for (int k = 0; k < 16; ++k) hs[k] = RDLANE(h, 4 * k);

        if (dostore)
          hq[(size_t)(ch * CHUNK + ts + u) * 16] = f2bf(h);
      }
    }

    __syncthreads();
    if (ch + 1 < NCH) {
      const unsigned short* xn = xs[(ch + 1) & 1];
#pragma unroll
      for (int u = 0; u < 8; ++u) buf[u] = bf2f(xn[u * 64 + lane]) * sfac;
    }
  }
}

// ---------------- Kernel 3: head + mean ----------------
__global__ __launch_bounds__(256) void k3_head(
    const unsigned short* __restrict__ hst,
    const float* __restrict__ W1, const float* __restrict__ b1,
    const float* __restrict__ W2, const float* __restrict__ b2,
    float* __restrict__ out)
{
  __shared__ float ws1[256];
  __shared__ float wsb1[16], wsw2[16];
  __shared__ float red[256];
  const int tid = threadIdx.x;
  const int b = blockIdx.x;

  ws1[tid] = W1[tid];
  if (tid < 16) { wsb1[tid] = b1[tid]; wsw2[tid] = W2[tid]; }
  __syncthreads();
  const float b2s = b2[0];

  float acc = 0.f;
#pragma unroll
  for (int it = 0; it < 4; ++it) {
    const int t = it * 256 + tid;
    const uint4* hp = reinterpret_cast<const uint4*>(hst + ((size_t)b * T_LEN + t) * 16);
    uint4 ha = hp[0], hb = hp[1];
    float h[16];
    h[0]  = bf2f((unsigned short)(ha.x & 0xffff)); h[1]  = bf2f((unsigned short)(ha.x >> 16));
    h[2]  = bf2f((unsigned short)(ha.y & 0xffff)); h[3]  = bf2f((unsigned short)(ha.y >> 16));
    h[4]  = bf2f((unsigned short)(ha.z & 0xffff)); h[5]  = bf2f((unsigned short)(ha.z >> 16));
    h[6]  = bf2f((unsigned short)(ha.w & 0xffff)); h[7]  = bf2f((unsigned short)(ha.w >> 16));
    h[8]  = bf2f((unsigned short)(hb.x & 0xffff)); h[9]  = bf2f((unsigned short)(hb.x >> 16));
    h[10] = bf2f((unsigned short)(hb.y & 0xffff)); h[11] = bf2f((unsigned short)(hb.y >> 16));
    h[12] = bf2f((unsigned short)(hb.z & 0xffff)); h[13] = bf2f((unsigned short)(hb.z >> 16));
    h[14] = bf2f((unsigned short)(hb.w & 0xffff)); h[15] = bf2f((unsigned short)(hb.w >> 16));

    float s = b2s;
#pragma unroll
    for (int jj = 0; jj < 16; ++jj) {
      float p = wsb1[jj];
#pragma unroll
      for (int k = 0; k < 16; ++k) p = fmaf(ws1[jj * 16 + k], h[k], p);
      p = fmaxf(p, 0.f);
      s = fmaf(wsw2[jj], p, s);
    }
    float e = fexp2(-LOG2E * s);
    acc += frcp(1.f + e);
  }

  red[tid] = acc;
  __syncthreads();
  if (tid < 128) red[tid] += red[tid + 128];
  __syncthreads();
  if (tid < 64) {
    float v = red[tid] + red[tid + 64];
    v += __shfl_xor(v, 32, 64);
    v += __shfl_xor(v, 16, 64);
    v += __shfl_xor(v, 8, 64);
    v += __shfl_xor(v, 4, 64);
    v += __shfl_xor(v, 2, 64);
    v += __shfl_xor(v, 1, 64);
    if (tid == 0) out[b] = v * (1.f / T_LEN);
  }
}

// ---------------- launcher ----------------
extern "C" void kernel_launch(void* const* d_in, const int* in_sizes, int n_in,
                              void* d_out, int out_size, void* d_ws, size_t ws_size,
                              hipStream_t stream) {
  const float* x   = (const float*)d_in[0];
  const float* h0  = (const float*)d_in[1];
  const float* c0  = (const float*)d_in[2];
  const float* Wih = (const float*)d_in[3];
  const float* Whh = (const float*)d_in[4];
  const float* bih = (const float*)d_in[5];
  const float* bhh = (const float*)d_in[6];
  const float* W1  = (const float*)d_in[7];
  const float* b1  = (const float*)d_in[8];
  const float* W2  = (const float*)d_in[9];
  const float* b2  = (const float*)d_in[10];

  char* wsb = (char*)d_ws;
  unsigned short* xproj = (unsigned short*)wsb;                         // 32 MiB
  unsigned short* hst   = (unsigned short*)(wsb + 33554432);            // 8 MiB
  bf16x8* wB            = (bf16x8*)(wsb + 33554432 + 8388608);          // 28672 B
  float* biasPerm       = (float*)(wsb + 33554432 + 8388608 + 28672);   // 256 B

  hipLaunchKernelGGL(k0_prep, dim3(7), dim3(256), 0, stream,
                     Wih, bih, bhh, wB, biasPerm);
  hipLaunchKernelGGL(k1_xproj, dim3(4096), dim3(256), 0, stream,
                     x, wB, biasPerm, xproj);
  hipLaunchKernelGGL(k2_scan, dim3(NB), dim3(64), 0, stream,
                     xproj, h0, c0, Whh, hst);
  hipLaunchKernelGGL(k3_head, dim3(NB), dim3(256), 0, stream,
                     hst, W1, b1, W2, b2, (float*)d_out);
}

// Round 6
// 165.080 us; speedup vs baseline: 3.2175x; 1.2157x over previous
//
#include <hip/hip_runtime.h>

// LSTMDiscriminator: B=256, T=1024, I=200, H=16
// K0: prepack W_ih (permuted cols, bf16, fragment-linear) + fused bias -> ws
// K1: x_proj = x @ W_ih^T + bias via MFMA 16x16x32 bf16; epilogue folds the
//     gate-dependent exp2 scale (sfac) into the stored bf16 values.
// K2: LSTM scan; xproj double-buffered in LDS via global_load_lds; recurrent
//     dot via v_dot2_f32_f16 with h packed as f16 pairs (8 readlanes).
// K3: head relu(h@W1^T+b1)@W2^T+b2 -> sigmoid -> mean over T.

#define T_LEN 1024
#define NB    256
#define CHUNK 128
#define NCH   (T_LEN / CHUNK)

#define F2I(x) __float_as_int(x)
#define I2F(x) __int_as_float(x)
#define DPPF(v, ctrl) I2F(__builtin_amdgcn_update_dpp(F2I(v), F2I(v), (ctrl), 0xF, 0xF, false))
// row_shl:4 (ctrl 0x104): lane i reads lane i+4 (shfl_down-style) -> h_{j+1}
#define ROWSHL4(v) I2F(__builtin_amdgcn_update_dpp(F2I(v), F2I(v), 0x104, 0xF, 0xF, false))
#define RDLANE_I(v, l) __builtin_amdgcn_readlane((v), (l))

#define LOG2E 1.442695040888963f

typedef __bf16 bf16_t;
typedef bf16_t bf16x8 __attribute__((ext_vector_type(8)));
typedef float f32x4 __attribute__((ext_vector_type(4)));
typedef __fp16 half2_t __attribute__((ext_vector_type(2)));   // matches builtin types

#if __has_builtin(__builtin_amdgcn_exp2f)
__device__ __forceinline__ float fexp2(float x) { return __builtin_amdgcn_exp2f(x); }
#else
__device__ __forceinline__ float fexp2(float x) { return exp2f(x); }
#endif
#if __has_builtin(__builtin_amdgcn_rcpf)
__device__ __forceinline__ float frcp(float x) { return __builtin_amdgcn_rcpf(x); }
#else
__device__ __forceinline__ float frcp(float x) { return __fdividef(1.f, x); }
#endif

__device__ __forceinline__ half2_t i2h2(int x) { union { int i; half2_t h; } u; u.i = x; return u.h; }
__device__ __forceinline__ int h22i(half2_t h) { union { int i; half2_t h; } u; u.h = h; return u.i; }

#if __has_builtin(__builtin_amdgcn_fdot2)
#define FDOT2(a, b, c) __builtin_amdgcn_fdot2((a), (b), (c), false)
#else
__device__ __forceinline__ float FDOT2(half2_t a, half2_t b, float c) {
  return c + (float)a[0] * (float)b[0] + (float)a[1] * (float)b[1];
}
#endif

__device__ __forceinline__ float bf2f(unsigned short s) {
  return __uint_as_float(((unsigned int)s) << 16);
}

// ---------------- Kernel 0: prepack W (bf16, fragment-linear) + bias ----------------
__global__ __launch_bounds__(256) void k0_prep(
    const float* __restrict__ Wih, const float* __restrict__ bih,
    const float* __restrict__ bhh, bf16x8* __restrict__ wB,
    float* __restrict__ biasPerm)
{
  const int idx = blockIdx.x * 256 + threadIdx.x;   // 0..1791
  if (idx < 4 * 7 * 64) {
    const int f = idx / 448;
    const int rem = idx % 448;
    const int s = rem / 64;
    const int L = rem % 64;
    const int col = f * 16 + (L & 15);
    const int r = ((col & 3) << 4) | (col >> 2);
    const int k0 = s * 32 + (L >> 4) * 8;
    bf16x8 v;
#pragma unroll
    for (int e = 0; e < 8; ++e) {
      const int k = k0 + e;
      const float w = (k < 200) ? Wih[r * 200 + k] : 0.f;
      v[e] = (bf16_t)w;
    }
    wB[idx] = v;
  }
  if (blockIdx.x == 0 && threadIdx.x < 64) {
    const int c = threadIdx.x;
    const int r = ((c & 3) << 4) | (c >> 2);
    biasPerm[c] = bih[r] + bhh[r];
  }
}

// ---------------- Kernel 1: x projection via MFMA ----------------
// grid = 4096 x 256 (4 waves). Block: 64 rows x 64 cols, K=224 (7 steps of 32).
__global__ __launch_bounds__(256) void k1_xproj(
    const float* __restrict__ x, const bf16x8* __restrict__ wB,
    const float* __restrict__ biasPerm, unsigned short* __restrict__ xproj)
{
  __shared__ bf16x8 As[4 * 7 * 64];   // 28672 B
  __shared__ bf16x8 Bs[4 * 7 * 64];   // 28672 B

  const int tid = threadIdx.x;
  const int L = tid & 63;
  const int w = tid >> 6;
  const long row0 = (long)blockIdx.x * 64;

  if (w == 0) {
    const unsigned short* src = (const unsigned short*)wB;
    unsigned short* dst = (unsigned short*)Bs;
#pragma unroll
    for (int it = 0; it < 28; ++it) {
      __builtin_amdgcn_global_load_lds(
          (const __attribute__((address_space(1))) unsigned int*)(src + it * 512 + L * 8),
          (__attribute__((address_space(3))) unsigned int*)(dst + it * 512),
          16, 0, 0);
    }
  }

  const float* xr = x + (row0 + w * 16 + (L & 15)) * 200;
  const int kg = (L >> 4) * 8;
#pragma unroll
  for (int s = 0; s < 7; ++s) {
    const int k0 = s * 32 + kg;
    bf16x8 v;
    if (k0 < 200) {
      float4 a = *reinterpret_cast<const float4*>(xr + k0);
      float4 b = *reinterpret_cast<const float4*>(xr + k0 + 4);
      v[0] = (bf16_t)a.x; v[1] = (bf16_t)a.y; v[2] = (bf16_t)a.z; v[3] = (bf16_t)a.w;
      v[4] = (bf16_t)b.x; v[5] = (bf16_t)b.y; v[6] = (bf16_t)b.z; v[7] = (bf16_t)b.w;
    } else {
      v[0] = (bf16_t)0.f; v[1] = (bf16_t)0.f; v[2] = (bf16_t)0.f; v[3] = (bf16_t)0.f;
      v[4] = (bf16_t)0.f; v[5] = (bf16_t)0.f; v[6] = (bf16_t)0.f; v[7] = (bf16_t)0.f;
    }
    As[(w * 7 + s) * 64 + L] = v;
  }

  __syncthreads();

  f32x4 acc0 = {0.f, 0.f, 0.f, 0.f};
  f32x4 acc1 = {0.f, 0.f, 0.f, 0.f};
  f32x4 acc2 = {0.f, 0.f, 0.f, 0.f};
  f32x4 acc3 = {0.f, 0.f, 0.f, 0.f};
#pragma unroll
  for (int s = 0; s < 7; ++s) {
    const bf16x8 a = As[(w * 7 + s) * 64 + L];
    acc0 = __builtin_amdgcn_mfma_f32_16x16x32_bf16(a, Bs[(0 * 7 + s) * 64 + L], acc0, 0, 0, 0);
    acc1 = __builtin_amdgcn_mfma_f32_16x16x32_bf16(a, Bs[(1 * 7 + s) * 64 + L], acc1, 0, 0, 0);
    acc2 = __builtin_amdgcn_mfma_f32_16x16x32_bf16(a, Bs[(2 * 7 + s) * 64 + L], acc2, 0, 0, 0);
    acc3 = __builtin_amdgcn_mfma_f32_16x16x32_bf16(a, Bs[(3 * 7 + s) * 64 + L], acc3, 0, 0, 0);
  }

  // epilogue: (acc + bias) * colscale, store bf16.
  const int cb = L & 15;
  const float cs = ((cb & 3) == 2) ? (-2.f * LOG2E) : (-LOG2E);
  const long rbase = row0 + w * 16 + ((L >> 4) << 2);
  __bf16* xo = (__bf16*)xproj;
  const float bv0 = biasPerm[0 * 16 + cb];
  const float bv1 = biasPerm[1 * 16 + cb];
  const float bv2 = biasPerm[2 * 16 + cb];
  const float bv3 = biasPerm[3 * 16 + cb];
#pragma unroll
  for (int q = 0; q < 4; ++q) {
    __bf16* row = xo + (rbase + q) * 64;
    row[ 0 + cb] = (bf16_t)((acc0[q] + bv0) * cs);
    row[16 + cb] = (bf16_t)((acc1[q] + bv1) * cs);
    row[32 + cb] = (bf16_t)((acc2[q] + bv2) * cs);
    row[48 + cb] = (bf16_t)((acc3[q] + bv3) * cs);
  }
}

// ---------------- Kernel 2: LSTM scan ----------------
__device__ __forceinline__ void stage_chunk(const unsigned short* g,
                                            unsigned short* l, int lane) {
#pragma unroll
  for (int it = 0; it < 16; ++it) {   // 16 x 1KB = 16KB (128 steps x 128B)
    __builtin_amdgcn_global_load_lds(
        (const __attribute__((address_space(1))) unsigned int*)(g + it * 512 + lane * 8),
        (__attribute__((address_space(3))) unsigned int*)(l + it * 512),
        16, 0, 0);
  }
}

// pack h (quad-uniform: lane 4j..4j+3 hold h[j]) into 8 wave-uniform f16-pairs.
// ROWSHL4 brings h[j+1] to lane 4j; harvest pairs at lanes 0,8,...,56.
#define PACKH(hval, d0,d1,d2,d3,d4,d5,d6,d7) do {            \
    float _hn = ROWSHL4(hval);                               \
    int _pk = h22i(__builtin_amdgcn_cvt_pkrtz((hval), _hn)); \
    d0 = RDLANE_I(_pk,  0); d1 = RDLANE_I(_pk,  8);          \
    d2 = RDLANE_I(_pk, 16); d3 = RDLANE_I(_pk, 24);          \
    d4 = RDLANE_I(_pk, 32); d5 = RDLANE_I(_pk, 40);          \
    d6 = RDLANE_I(_pk, 48); d7 = RDLANE_I(_pk, 56);          \
  } while (0)

__global__ __launch_bounds__(64, 1) void k2_scan(
    const unsigned short* __restrict__ xproj,
    const float* __restrict__ h0, const float* __restrict__ c0,
    const float* __restrict__ Whh,
    unsigned short* __restrict__ hst)
{
  __shared__ unsigned short xs[2][CHUNK * 64];    // 2 x 16KB
  const int b = blockIdx.x;
  const int lane = threadIdx.x;
  const int g = lane & 3;
  const int j = lane >> 2;
  const int r = (g << 4) | j;

  const unsigned short* gx = xproj + (size_t)b * (T_LEN * 64);
  stage_chunk(gx, xs[0], lane);                   // chunk 0 in flight

  const float sfac = (g == 2) ? (-2.f * LOG2E) : (-LOG2E);
  const float pfac = (g == 2) ?  2.f :  1.f;
  const float qfac = (g == 2) ? -1.f :  0.f;

  // recurrent weights as f16 pairs, scaled by sfac
  half2_t wpk[8];
#pragma unroll
  for (int q = 0; q < 4; ++q) {
    float4 w = *reinterpret_cast<const float4*>(Whh + r * 16 + q * 4);
    wpk[q * 2 + 0] = __builtin_amdgcn_cvt_pkrtz(w.x * sfac, w.y * sfac);
    wpk[q * 2 + 1] = __builtin_amdgcn_cvt_pkrtz(w.z * sfac, w.w * sfac);
  }

  float c = c0[b * 16 + j];
  float hmine = h0[b * 16 + j];
  // make h quad-uniform like the steady state (each lane in quad holds h[j])
  hmine = DPPF(hmine, 0x00);   // quad_perm[0,0,0,0] on h0 value loaded per-lane?
  // NOTE: h0 was loaded as h0[b*16+j] with j = lane>>2, so it is already
  // quad-uniform; the DPP above is a no-op kept for clarity of the invariant.

  int hp0, hp1, hp2, hp3, hp4, hp5, hp6, hp7;
  PACKH(hmine, hp0, hp1, hp2, hp3, hp4, hp5, hp6, hp7);

  unsigned short* hq = hst + (size_t)b * (T_LEN * 16) + j;  // quad lanes same addr

  __syncthreads();                                // chunk 0 staged

  float buf[8];
#pragma unroll
  for (int u = 0; u < 8; ++u)
    buf[u] = bf2f(xs[0][u * 64 + lane]);          // sfac already folded in

  for (int ch = 0; ch < NCH; ++ch) {
    const unsigned short* xcur = xs[ch & 1];
    if (ch + 1 < NCH) stage_chunk(gx + (ch + 1) * (CHUNK * 64),
                                  (unsigned short*)xs[(ch + 1) & 1], lane);

    for (int ts = 0; ts < CHUNK; ts += 8) {
#pragma unroll
      for (int u = 0; u < 8; ++u) {
        const float gin = buf[u];
        int tn = ts + 8 + u;
        tn = (tn < CHUNK) ? tn : (CHUNK - 1);
        buf[u] = bf2f(xcur[tn * 64 + lane]);

        // pre' = sfac * (gin_raw + Whh h): 2 chains of 4 dot2 + combine
        float d0 = FDOT2(wpk[0], i2h2(hp0), gin);
        d0 = FDOT2(wpk[1], i2h2(hp1), d0);
        d0 = FDOT2(wpk[2], i2h2(hp2), d0);
        d0 = FDOT2(wpk[3], i2h2(hp3), d0);
        float d1 = FDOT2(wpk[4], i2h2(hp4), 0.f);
        d1 = FDOT2(wpk[5], i2h2(hp5), d1);
        d1 = FDOT2(wpk[6], i2h2(hp6), d1);
        d1 = FDOT2(wpk[7], i2h2(hp7), d1);
        float pre = d0 + d1;

        float e = fexp2(pre);
        float z = frcp(1.f + e);
        float y = fmaf(pfac, z, qfac);            // sigmoid or tanh

        float ai = DPPF(y, 0x00);
        float af = DPPF(y, 0x55);
        float ag = DPPF(y, 0xAA);
        float ao = DPPF(y, 0xFF);

        c = fmaf(af, c, ai * ag);
        float e2 = fexp2((2.f * LOG2E) * c);
        float th = fmaf(-2.f, frcp(1.f + e2), 1.f);
        float h = ao * th;                        // quad-uniform

        PACKH(h, hp0, hp1, hp2, hp3, hp4, hp5, hp6, hp7);

        bf16_t hb = (bf16_t)h;
        hq[(size_t)(ch * CHUNK + ts + u) * 16] =
            *reinterpret_cast<unsigned short*>(&hb);
      }
    }

    __syncthreads();
    if (ch + 1 < NCH) {
      const unsigned short* xn = xs[(ch + 1) & 1];
#pragma unroll
      for (int u = 0; u < 8; ++u) buf[u] = bf2f(xn[u * 64 + lane]);
    }
  }
}

// ---------------- Kernel 3: head + mean ----------------
__global__ __launch_bounds__(256) void k3_head(
    const unsigned short* __restrict__ hst,
    const float* __restrict__ W1, const float* __restrict__ b1,
    const float* __restrict__ W2, const float* __restrict__ b2,
    float* __restrict__ out)
{
  __shared__ float ws1[256];
  __shared__ float wsb1[16], wsw2[16];
  __shared__ float red[256];
  const int tid = threadIdx.x;
  const int b = blockIdx.x;

  ws1[tid] = W1[tid];
  if (tid < 16) { wsb1[tid] = b1[tid]; wsw2[tid] = W2[tid]; }
  __syncthreads();
  const float b2s = b2[0];

  float acc = 0.f;
#pragma unroll
  for (int it = 0; it < 4; ++it) {
    const int t = it * 256 + tid;
    const uint4* hp = reinterpret_cast<const uint4*>(hst + ((size_t)b * T_LEN + t) * 16);
    uint4 ha = hp[0], hb = hp[1];
    float h[16];
    h[0]  = bf2f((unsigned short)(ha.x & 0xffff)); h[1]  = bf2f((unsigned short)(ha.x >> 16));
    h[2]  = bf2f((unsigned short)(ha.y & 0xffff)); h[3]  = bf2f((unsigned short)(ha.y >> 16));
    h[4]  = bf2f((unsigned short)(ha.z & 0xffff)); h[5]  = bf2f((unsigned short)(ha.z >> 16));
    h[6]  = bf2f((unsigned short)(ha.w & 0xffff)); h[7]  = bf2f((unsigned short)(ha.w >> 16));
    h[8]  = bf2f((unsigned short)(hb.x & 0xffff)); h[9]  = bf2f((unsigned short)(hb.x >> 16));
    h[10] = bf2f((unsigned short)(hb.y & 0xffff)); h[11] = bf2f((unsigned short)(hb.y >> 16));
    h[12] = bf2f((unsigned short)(hb.z & 0xffff)); h[13] = bf2f((unsigned short)(hb.z >> 16));
    h[14] = bf2f((unsigned short)(hb.w & 0xffff)); h[15] = bf2f((unsigned short)(hb.w >> 16));

    float s = b2s;
#pragma unroll
    for (int jj = 0; jj < 16; ++jj) {
      float p = wsb1[jj];
#pragma unroll
      for (int k = 0; k < 16; ++k) p = fmaf(ws1[jj * 16 + k], h[k], p);
      p = fmaxf(p, 0.f);
      s = fmaf(wsw2[jj], p, s);
    }
    float e = fexp2(-LOG2E * s);
    acc += frcp(1.f + e);
  }

  red[tid] = acc;
  __syncthreads();
  if (tid < 128) red[tid] += red[tid + 128];
  __syncthreads();
  if (tid < 64) {
    float v = red[tid] + red[tid + 64];
    v += __shfl_xor(v, 32, 64);
    v += __shfl_xor(v, 16, 64);
    v += __shfl_xor(v, 8, 64);
    v += __shfl_xor(v, 4, 64);
    v += __shfl_xor(v, 2, 64);
    v += __shfl_xor(v, 1, 64);
    if (tid == 0) out[b] = v * (1.f / T_LEN);
  }
}

// ---------------- launcher ----------------
extern "C" void kernel_launch(void* const* d_in, const int* in_sizes, int n_in,
                              void* d_out, int out_size, void* d_ws, size_t ws_size,
                              hipStream_t stream) {
  const float* x   = (const float*)d_in[0];
  const float* h0  = (const float*)d_in[1];
  const float* c0  = (const float*)d_in[2];
  const float* Wih = (const float*)d_in[3];
  const float* Whh = (const float*)d_in[4];
  const float* bih = (const float*)d_in[5];
  const float* bhh = (const float*)d_in[6];
  const float* W1  = (const float*)d_in[7];
  const float* b1  = (const float*)d_in[8];
  const float* W2  = (const float*)d_in[9];
  const float* b2  = (const float*)d_in[10];

  char* wsb = (char*)d_ws;
  unsigned short* xproj = (unsigned short*)wsb;                         // 32 MiB
  unsigned short* hst   = (unsigned short*)(wsb + 33554432);            // 8 MiB
  bf16x8* wB            = (bf16x8*)(wsb + 33554432 + 8388608);          // 28672 B
  float* biasPerm       = (float*)(wsb + 33554432 + 8388608 + 28672);   // 256 B

  hipLaunchKernelGGL(k0_prep, dim3(7), dim3(256), 0, stream,
                     Wih, bih, bhh, wB, biasPerm);
  hipLaunchKernelGGL(k1_xproj, dim3(4096), dim3(256), 0, stream,
                     x, wB, biasPerm, xproj);
  hipLaunchKernelGGL(k2_scan, dim3(NB), dim3(64), 0, stream,
                     xproj, h0, c0, Whh, hst);
  hipLaunchKernelGGL(k3_head, dim3(NB), dim3(256), 0, stream,
                     hst, W1, b1, W2, b2, (float*)d_out);
}